// Round 1
// 622.057 us; speedup vs baseline: 1.2408x; 1.2408x over previous
//
#include <hip/hip_runtime.h>
#include <math.h>

typedef __attribute__((ext_vector_type(8))) _Float16 half8;
typedef __attribute__((ext_vector_type(4))) _Float16 half4v;
typedef __attribute__((ext_vector_type(4))) float f32x4;

// ---------------- problem constants ----------------
constexpr int cB = 32, cNP = 2000, cS = 100, cL = 60, cE = 300;
constexpr int cQ = 50, cDD = 100, cDH = 50;
constexpr float cNEG = 1.0e12f;

// ---------------- workspace layout (float units) ----------------
constexpr size_t OFF_REL  = 0;        // B*Q*S = 160000
constexpr size_t OFF_RG   = 160000;   // B*Q*E = 480000 (fp32 gathered report emb)
constexpr size_t OFF_RNRM = 640000;   // B*Q
constexpr size_t OFF_IDFW = 641600;   // B*Q
constexpr size_t OFF_W1TH = 643200;   // 112*304 f16 = 17024 floats
constexpr size_t OFF_W1TL = 660224;   // 17024
constexpr size_t OFF_W2TH = 677248;   // 64*128 f16 = 4096 floats
constexpr size_t OFF_W2TL = 681344;   // 4096

// ---------------- LDS byte offsets (kernelA) ----------------
constexpr int LDS_CL    = 0;         // [60][300] f32
constexpr int LDS_AL    = 72000;     // [50][60] f32
constexpr int LDS_AVF   = 84000;     // [50][300] f32
constexpr int LDS_G_HI  = 0;         // f16 [64 q][320 e] swizzled (overlays CL)
constexpr int LDS_G_LO  = 40960;     // rows are 640 B (multiple of 128 -> safe XOR swizzle)
constexpr int LDS_H1    = 84000;     // f32 [64][128] (overlays AVF)
constexpr int LDS_H2    = 116768;    // f32 [50][68]
constexpr int LDS_SCL   = 144000;    // f32 [64]
constexpr int LDS_WORDS = 144256;    // int [64]
constexpr int LDS_TOTAL = 144512;

__device__ __forceinline__ _Float16 h_hi(float f) { return (_Float16)f; }
__device__ __forceinline__ _Float16 h_lo(float f, _Float16 h) { return (_Float16)(f - (float)h); }
// block-local XOR swizzle: permutes only within each 128-byte block -> never leaves the row
__device__ __forceinline__ int bswz(int cb, int row) {
    return (cb & ~127) | ((cb & 127) ^ ((row & 7) << 4));
}

// ---------------- prep: pack W1^T, W2^T as fp16 hi/lo, zero-padded ----------------
__global__ void prep_weights(const float* __restrict__ W1, const float* __restrict__ W2,
                             _Float16* __restrict__ W1TH, _Float16* __restrict__ W1TL,
                             _Float16* __restrict__ W2TH, _Float16* __restrict__ W2TL)
{
    int tid = blockIdx.x * blockDim.x + threadIdx.x;
    int stride = gridDim.x * blockDim.x;
    for (int idx = tid; idx < 112 * 304; idx += stride) {
        int d = idx / 304, e = idx % 304;
        float w = (d < cDD && e < cE) ? W1[(size_t)e * cDD + d] : 0.f;
        _Float16 h = h_hi(w);
        W1TH[idx] = h; W1TL[idx] = h_lo(w, h);
    }
    for (int idx = tid; idx < 64 * 128; idx += stride) {
        int j = idx / 128, d = idx % 128;
        float w = (j < cDH && d < cDD) ? W2[(size_t)d * cDH + j] : 0.f;
        _Float16 h = h_hi(w);
        W2TH[idx] = h; W2TL[idx] = h_lo(w, h);
    }
}

// ---------------- prep per-batch: gather R fp32, norms, idf softmax ----------------
__global__ __launch_bounds__(256) void prep_batch(
    const int* __restrict__ r_idx,
    const float* __restrict__ report_table,
    const float* __restrict__ report_word_emb,
    const float* __restrict__ idf_table,
    float* __restrict__ Rg, float* __restrict__ rnorm, float* __restrict__ idfw)
{
    int b = blockIdx.x, tid = threadIdx.x;
    __shared__ int rv[cQ];
    if (tid < cQ) rv[tid] = (int)report_table[(size_t)r_idx[b] * cQ + tid];
    __syncthreads();
    float* dst = Rg + (size_t)b * cQ * cE;
    for (int idx = tid; idx < cQ * 75; idx += 256) {
        int q = idx / 75, e4 = idx % 75;
        f32x4 v = *(const f32x4*)(report_word_emb + (size_t)rv[q] * cE + e4 * 4);
        *(f32x4*)(dst + (size_t)q * cE + e4 * 4) = v;
    }
    __syncthreads();
    if (tid < cQ) {
        const float* row = dst + (size_t)tid * cE;
        float ss = 0.f;
        for (int e = 0; e < cE; e += 4) {
            f32x4 v = *(const f32x4*)(row + e);
            ss += v[0]*v[0] + v[1]*v[1] + v[2]*v[2] + v[3]*v[3];
        }
        rnorm[b * cQ + tid] = sqrtf(ss);
    }
    if (tid < 64) {
        float x = -INFINITY;
        if (tid < cQ) {
            float w = idf_table[rv[tid]];
            x = (w == 0.0f) ? -cNEG : w;
        }
        float m = x;
        for (int o = 32; o; o >>= 1) m = fmaxf(m, __shfl_xor(m, o));
        float e = (tid < cQ) ? expf(x - m) : 0.f;
        float ssum = e;
        for (int o = 32; o; o >>= 1) ssum += __shfl_xor(ssum, o);
        if (tid < cQ) idfw[b * cQ + tid] = e / ssum;
    }
}

// ---------------- main kernel: one block per (b, s), 512 threads ----------------
// 512 threads = 8 waves/CU = 2 waves/SIMD (LDS still limits to 1 block/CU).
// All per-output arithmetic sequences are IDENTICAL to the 256-thread version
// (bit-exact output) -- only the thread->output assignment changed.
__global__ __launch_bounds__(512, 1) void kernelA(
    const int* __restrict__ r_idx, const int* __restrict__ c_idx,
    const float* __restrict__ matrix, const float* __restrict__ code_table,
    const float* __restrict__ snippet_table, const float* __restrict__ code_word_emb,
    const float* __restrict__ snippet_len_table,
    const float* __restrict__ Rg, const float* __restrict__ rnorm,
    const _Float16* __restrict__ W1TH, const _Float16* __restrict__ W1TL, const float* __restrict__ b1,
    const _Float16* __restrict__ W2TH, const _Float16* __restrict__ W2TL, const float* __restrict__ b2,
    const float* __restrict__ W3, const float* __restrict__ b3,
    float* __restrict__ rel_out)
{
    const int s = blockIdx.x, b = blockIdx.y;
    const int tid = threadIdx.x;
    const int lane = tid & 63, wid = tid >> 6;
    const int n = lane & 15, gl = lane >> 4;     // MFMA fragment coords

    __shared__ __align__(16) unsigned char smem[LDS_TOTAL];
    int*   words = (int*)(smem + LDS_WORDS);
    float* sclp  = (float*)(smem + LDS_SCL);
    float* Cl    = (float*)(smem + LDS_CL);      // [60][300] fp32
    float* Alp   = (float*)(smem + LDS_AL);      // [50][60] fp32
    float* AVf   = (float*)(smem + LDS_AVF);     // [50][300] fp32

    const int rr = r_idx[b], cc = c_idx[b];
    const int code = (int)matrix[(size_t)rr * cNP + cc];
    const int snip = (int)code_table[(size_t)code * cS + s];
    const int slen = (int)snippet_len_table[snip];

    if (tid < cL) words[tid] = (int)snippet_table[(size_t)snip * cL + tid];
    if (tid < cQ) sclp[tid] = 0.f;
    __syncthreads();

    // ---- gather snippet embeddings: fp32 row-major [60][300]
    for (int idx = tid; idx < cL * 75; idx += 512) {
        int l = idx / 75, e4 = idx % 75;
        f32x4 v = *(const f32x4*)(code_word_emb + (size_t)words[l] * cE + e4 * 4);
        *(f32x4*)(Cl + l * 300 + e4 * 4) = v;
    }
    __syncthreads();

    // ---- scores[q][l] = sum_e r[q][e]*C[l][e]  (round-1-exact fp32) ----
    // thread (qt = tid>>5, lt2 = tid&31) owns q = qt+16i (i<4), l = lt2+32j (j<2)
    {
        const int qt = tid >> 5, lt2 = tid & 31;
        float acc[4][2];
        #pragma unroll
        for (int i = 0; i < 4; i++)
            #pragma unroll
            for (int j = 0; j < 2; j++) acc[i][j] = 0.f;
        const float* rbase = Rg + (size_t)b * cQ * cE;
        const float* rrow[4];
        #pragma unroll
        for (int i = 0; i < 4; i++) {
            int q = qt + 16 * i;
            rrow[i] = rbase + (size_t)(q < cQ ? q : 0) * cE;
        }
        int lrow[2];
        #pragma unroll
        for (int j = 0; j < 2; j++) {
            int l = lt2 + 32 * j;
            lrow[j] = (l < cL) ? l : 0;
        }
        for (int e = 0; e < cE; e += 4) {
            f32x4 rv[4], cv[2];
            #pragma unroll
            for (int i = 0; i < 4; i++) rv[i] = *(const f32x4*)(rrow[i] + e);
            #pragma unroll
            for (int j = 0; j < 2; j++) cv[j] = *(const f32x4*)(Cl + lrow[j] * 300 + e);
            #pragma unroll
            for (int i = 0; i < 4; i++)
                #pragma unroll
                for (int j = 0; j < 2; j++)
                    acc[i][j] += rv[i][0] * cv[j][0] + rv[i][1] * cv[j][1] +
                                 rv[i][2] * cv[j][2] + rv[i][3] * cv[j][3];
        }
        #pragma unroll
        for (int i = 0; i < 4; i++) {
            int q = qt + 16 * i;
            if (q >= cQ) continue;
            #pragma unroll
            for (int j = 0; j < 2; j++) {
                int l = lt2 + 32 * j;
                if (l >= cL) continue;
                Alp[q * 60 + l] = acc[i][j] - ((l >= slen) ? cNEG : 0.f);
            }
        }
    }
    __syncthreads();

    // ---- softmax over l (round-1-exact; identical mapping & reduce order) ----
    {
        const int g2 = tid >> 2, k = tid & 3;
        if (g2 < cQ) {
            float v[15];
            float m = -INFINITY;
            #pragma unroll
            for (int t = 0; t < 15; t++) { v[t] = Alp[g2 * 60 + k + 4 * t]; m = fmaxf(m, v[t]); }
            m = fmaxf(m, __shfl_xor(m, 1));
            m = fmaxf(m, __shfl_xor(m, 2));
            float sum = 0.f;
            #pragma unroll
            for (int t = 0; t < 15; t++) { v[t] = expf(v[t] - m); sum += v[t]; }
            sum += __shfl_xor(sum, 1);
            sum += __shfl_xor(sum, 2);
            float inv = 1.0f / sum;
            #pragma unroll
            for (int t = 0; t < 15; t++) Alp[g2 * 60 + k + 4 * t] = v[t] * inv;
        }
    }
    __syncthreads();

    // ---- av[q][e] = sum_l a[q][l]*C[l][e] (round-1-exact fp32) ----
    // l-loop OUTER: a[q][l] read once per l (2.5x fewer scalar LDS reads).
    // thread (qt3 = tid>>5, et3 = tid&31) owns q = qt3+16i (i<4), e4 = et3+32jj (jj<3)
    {
        const int qt3 = tid >> 5, et3 = tid & 31;
        const float* arow[4];
        int qv[4];
        #pragma unroll
        for (int i = 0; i < 4; i++) {
            int q = qt3 + 16 * i;
            qv[i] = q;
            arow[i] = Alp + (size_t)((q < cQ) ? q : 0) * 60;
        }
        int e4v[3], e4c[3];
        #pragma unroll
        for (int jj = 0; jj < 3; jj++) {
            e4v[jj] = et3 + 32 * jj;
            e4c[jj] = (e4v[jj] < 75) ? e4v[jj] : 0;
        }
        f32x4 acc4[4][3];
        #pragma unroll
        for (int i = 0; i < 4; i++)
            #pragma unroll
            for (int jj = 0; jj < 3; jj++) acc4[i][jj] = (f32x4){0.f, 0.f, 0.f, 0.f};
        for (int l = 0; l < cL; l++) {
            float av[4];
            #pragma unroll
            for (int i = 0; i < 4; i++) av[i] = arow[i][l];
            f32x4 cv[3];
            #pragma unroll
            for (int jj = 0; jj < 3; jj++) cv[jj] = *(const f32x4*)(Cl + l * 300 + e4c[jj] * 4);
            #pragma unroll
            for (int i = 0; i < 4; i++)
                #pragma unroll
                for (int jj = 0; jj < 3; jj++) {
                    acc4[i][jj][0] += av[i] * cv[jj][0];
                    acc4[i][jj][1] += av[i] * cv[jj][1];
                    acc4[i][jj][2] += av[i] * cv[jj][2];
                    acc4[i][jj][3] += av[i] * cv[jj][3];
                }
        }
        #pragma unroll
        for (int i = 0; i < 4; i++)
            #pragma unroll
            for (int jj = 0; jj < 3; jj++)
                if (e4v[jj] < 75 && qv[i] < cQ)
                    *(f32x4*)(AVf + qv[i] * 300 + e4v[jj] * 4) = acc4[i][jj];
    }
    __syncthreads();

    // ---- sum-of-squares of av (EXACT old mapping + reduce order, reads back fp32) ----
    if (tid < 256) {
        const int qs = tid >> 4, es = tid & 15;
        #pragma unroll
        for (int jj = 0; jj < 5; jj++) {
            int e4 = es + 16 * jj;
            int e4cl = (e4 < 75) ? e4 : 0;
            #pragma unroll
            for (int i = 0; i < 4; i++) {
                int q = qs + 16 * i;
                int qcl = (q < cQ) ? q : 0;
                f32x4 v = *(const f32x4*)(AVf + qcl * 300 + e4cl * 4);
                bool valid = (e4 < 75) && (q < cQ);
                float dv = valid ? (v[0]*v[0] + v[1]*v[1] + v[2]*v[2] + v[3]*v[3]) : 0.f;
                dv += __shfl_xor(dv, 1);
                dv += __shfl_xor(dv, 2);
                dv += __shfl_xor(dv, 4);
                dv += __shfl_xor(dv, 8);
                if (es == 0 && q < cQ) sclp[q] += dv;
            }
        }
    }
    __syncthreads();

    // finalize scale = 1/(|r|*|av|)  (0-guard == reference NaN fix)
    if (tid < cQ) {
        float p = rnorm[b * cQ + tid] * sqrtf(sclp[tid]);
        sclp[tid] = (p > 0.f) ? (1.0f / p) : 0.f;
    }

    // ---- g = r .* av -> f16 hi/lo [64 q][320 e], block-swizzled rows of 640 B ----
    {
        const float* RgB = Rg + (size_t)b * cQ * cE;
        for (int idx = tid; idx < 64 * 80; idx += 512) {
            int q = idx / 80, e4 = idx % 80;
            half4v h4 = {0, 0, 0, 0}, l4 = {0, 0, 0, 0};
            if (q < cQ && e4 < 75) {
                f32x4 av4 = *(const f32x4*)(AVf + q * 300 + e4 * 4);
                f32x4 rv4 = *(const f32x4*)(RgB + (size_t)q * cE + e4 * 4);
                #pragma unroll
                for (int k = 0; k < 4; k++) {
                    float gf = av4[k] * rv4[k];
                    h4[k] = h_hi(gf);
                    l4[k] = h_lo(gf, h4[k]);
                }
            }
            int bo = q * 640 + bswz(8 * e4, q);
            *(half4v*)(smem + LDS_G_HI + bo) = h4;
            *(half4v*)(smem + LDS_G_LO + bo) = l4;
        }
    }
    __syncthreads();

    // ---- h1 = tanh(scale*(g@W1)+b1): MFMA, wave wid owns d-tile dt = wid (<7) ----
    {
        const half8 z8 = {0,0,0,0,0,0,0,0};
        const int dt = wid;
        f32x4 accH[4];
        #pragma unroll
        for (int q2 = 0; q2 < 4; q2++) accH[q2] = (f32x4){0.f, 0.f, 0.f, 0.f};
        if (dt < 7) {
            #pragma unroll
            for (int ks = 0; ks < 10; ks++) {
                bool lv = (ks != 9) || (gl < 2);
                half8 gh[4], glo[4];
                #pragma unroll
                for (int q2 = 0; q2 < 4; q2++) {
                    gh[q2] = z8; glo[q2] = z8;
                    if (lv) {
                        int q = 16 * q2 + n;
                        int bo = q * 640 + bswz(64 * ks + 16 * gl, q);
                        gh[q2]  = *(const half8*)(smem + LDS_G_HI + bo);
                        glo[q2] = *(const half8*)(smem + LDS_G_LO + bo);
                    }
                }
                half8 wh = z8, wl = z8;
                if (lv) {
                    int d = 16 * dt + n;
                    wh = *(const half8*)(W1TH + (size_t)d * 304 + 32 * ks + 8 * gl);
                    wl = *(const half8*)(W1TL + (size_t)d * 304 + 32 * ks + 8 * gl);
                }
                #pragma unroll
                for (int q2 = 0; q2 < 4; q2++) {
                    accH[q2] = __builtin_amdgcn_mfma_f32_16x16x32_f16(gh[q2],  wh, accH[q2], 0, 0, 0);
                    accH[q2] = __builtin_amdgcn_mfma_f32_16x16x32_f16(gh[q2],  wl, accH[q2], 0, 0, 0);
                    accH[q2] = __builtin_amdgcn_mfma_f32_16x16x32_f16(glo[q2], wh, accH[q2], 0, 0, 0);
                }
            }
        }
        float* h1p = (float*)(smem + LDS_H1);
        if (dt < 7) {
            int d = 16 * dt + n;
            #pragma unroll
            for (int q2 = 0; q2 < 4; q2++)
                #pragma unroll
                for (int r = 0; r < 4; r++) {
                    int q = 16 * q2 + 4 * gl + r;
                    if (q < cQ) {
                        float v = (d < cDD) ? tanhf(accH[q2][r] * sclp[q] + b1[d]) : 0.f;
                        h1p[q * 128 + d] = v;
                    }
                }
        }
        for (int idx = tid; idx < cQ * 16; idx += 512) {     // zero cols 112..127
            int q = idx >> 4, d = 112 + (idx & 15);
            h1p[q * 128 + d] = 0.f;
        }
    }
    __syncthreads();

    // ---- h2 = tanh(h1@W2+b2): MFMA; waves 0-3 do q2 {0,1}, waves 4-7 do q2 {2,3} ----
    {
        const float* h1p = (const float*)(smem + LDS_H1);
        const int jw = 16 * (wid & 3) + n;
        const int q2b = (wid >> 2) * 2;
        f32x4 accJ[2];
        #pragma unroll
        for (int t = 0; t < 2; t++) accJ[t] = (f32x4){0.f, 0.f, 0.f, 0.f};
        #pragma unroll
        for (int ks = 0; ks < 4; ks++) {
            half8 hh[2], hl[2];
            #pragma unroll
            for (int t = 0; t < 2; t++) {
                int q = 16 * (q2b + t) + n;
                const float* p = h1p + q * 128 + 32 * ks + 8 * gl;
                f32x4 fa = *(const f32x4*)p;
                f32x4 fb = *(const f32x4*)(p + 4);
                half8 h8, l8;
                #pragma unroll
                for (int jj = 0; jj < 8; jj++) {
                    float f = (jj < 4) ? fa[jj] : fb[jj - 4];
                    _Float16 h = h_hi(f);
                    h8[jj] = h;
                    l8[jj] = h_lo(f, h);
                }
                hh[t] = h8; hl[t] = l8;
            }
            half8 wh = *(const half8*)(W2TH + (size_t)jw * 128 + 32 * ks + 8 * gl);
            half8 wl = *(const half8*)(W2TL + (size_t)jw * 128 + 32 * ks + 8 * gl);
            #pragma unroll
            for (int t = 0; t < 2; t++) {
                accJ[t] = __builtin_amdgcn_mfma_f32_16x16x32_f16(hh[t], wh, accJ[t], 0, 0, 0);
                accJ[t] = __builtin_amdgcn_mfma_f32_16x16x32_f16(hh[t], wl, accJ[t], 0, 0, 0);
                accJ[t] = __builtin_amdgcn_mfma_f32_16x16x32_f16(hl[t], wh, accJ[t], 0, 0, 0);
            }
        }
        float* h2p = (float*)(smem + LDS_H2);
        #pragma unroll
        for (int t = 0; t < 2; t++)
            #pragma unroll
            for (int r = 0; r < 4; r++) {
                int q = 16 * (q2b + t) + 4 * gl + r;
                if (q < cQ && jw < cDH) h2p[q * 68 + jw] = tanhf(accJ[t][r] + b2[jw]);
            }
    }
    __syncthreads();

    // ---- rel[q] = tanh(h2 @ W3 + b3) ----
    if (tid < cQ) {
        const float* h2p = (const float*)(smem + LDS_H2);
        float a = b3[0];
        #pragma unroll 10
        for (int jj = 0; jj < cDH; jj++) a += h2p[tid * 68 + jj] * W3[jj];
        rel_out[((size_t)b * cQ + tid) * cS + s] = tanhf(a);
    }
}

// ---------------- per-batch: c_mask, top-5, Wk fusion, idf-weighted sum ----------------
__global__ __launch_bounds__(64) void kernelB(
    const float* __restrict__ rel_ws, const float* __restrict__ idfw,
    const int* __restrict__ c_idx, const float* __restrict__ code_len_table,
    const float* __restrict__ Wk, const float* __restrict__ bk,
    float* __restrict__ out)
{
    int b = blockIdx.x, q = threadIdx.x;
    float val = 0.f;
    if (q < cQ) {
        int clen = (int)code_len_table[c_idx[b]];
        const float* row = rel_ws + ((size_t)b * cQ + q) * cS;
        float t0 = -INFINITY, t1 = -INFINITY, t2 = -INFINITY, t3 = -INFINITY, t4 = -INFINITY;
        for (int s = 0; s < cS; s++) {
            float v = row[s] * ((s < clen) ? 1.f : 0.f);
            float m0 = fmaxf(t0, v), n0 = fminf(t0, v);
            float m1 = fmaxf(t1, n0), n1 = fminf(t1, n0);
            float m2 = fmaxf(t2, n1), n2 = fminf(t2, n1);
            float m3 = fmaxf(t3, n2), n3 = fminf(t3, n2);
            float m4 = fmaxf(t4, n3);
            t0 = m0; t1 = m1; t2 = m2; t3 = m3; t4 = m4;
        }
        float rc = t0 * Wk[0] + t1 * Wk[1] + t2 * Wk[2] + t3 * Wk[3] + t4 * Wk[4] + bk[0];
        val = rc * idfw[b * cQ + q];
    }
    for (int o = 32; o; o >>= 1) val += __shfl_down(val, o);
    if (q == 0) out[b] = val;
}

extern "C" void kernel_launch(void* const* d_in, const int* in_sizes, int n_in,
                              void* d_out, int out_size, void* d_ws, size_t ws_size,
                              hipStream_t stream)
{
    const int*   r_idx             = (const int*)d_in[0];
    const int*   c_idx             = (const int*)d_in[1];
    const float* matrix            = (const float*)d_in[2];
    const float* report_table      = (const float*)d_in[3];
    const float* report_word_emb   = (const float*)d_in[4];
    const float* idf_table         = (const float*)d_in[5];
    const float* code_table        = (const float*)d_in[6];
    const float* snippet_table     = (const float*)d_in[7];
    const float* code_word_emb     = (const float*)d_in[8];
    const float* snippet_len_table = (const float*)d_in[9];
    const float* code_len_table    = (const float*)d_in[10];
    const float* W1 = (const float*)d_in[11];
    const float* b1 = (const float*)d_in[12];
    const float* W2 = (const float*)d_in[13];
    const float* b2 = (const float*)d_in[14];
    const float* W3 = (const float*)d_in[15];
    const float* b3 = (const float*)d_in[16];
    const float* Wk = (const float*)d_in[17];
    const float* bk = (const float*)d_in[18];
    float* out = (float*)d_out;
    float* ws  = (float*)d_ws;

    float* rel_ws = ws + OFF_REL;
    float* Rg     = ws + OFF_RG;
    float* rnormp = ws + OFF_RNRM;
    float* idfwp  = ws + OFF_IDFW;
    _Float16* W1THp = (_Float16*)(ws + OFF_W1TH);
    _Float16* W1TLp = (_Float16*)(ws + OFF_W1TL);
    _Float16* W2THp = (_Float16*)(ws + OFF_W2TH);
    _Float16* W2TLp = (_Float16*)(ws + OFF_W2TL);

    prep_weights<<<64, 256, 0, stream>>>(W1, W2, W1THp, W1TLp, W2THp, W2TLp);
    prep_batch<<<cB, 256, 0, stream>>>(r_idx, report_table, report_word_emb, idf_table,
                                       Rg, rnormp, idfwp);
    kernelA<<<dim3(cS, cB), 512, 0, stream>>>(r_idx, c_idx, matrix, code_table,
                                              snippet_table, code_word_emb, snippet_len_table,
                                              Rg, rnormp,
                                              W1THp, W1TLp, b1, W2THp, W2TLp, b2, W3, b3, rel_ws);
    kernelB<<<cB, 64, 0, stream>>>(rel_ws, idfwp, c_idx, code_len_table, Wk, bk, out);
}

// Round 2
// 558.017 us; speedup vs baseline: 1.3832x; 1.1148x over previous
//
#include <hip/hip_runtime.h>
#include <math.h>

typedef __attribute__((ext_vector_type(8))) _Float16 half8;
typedef __attribute__((ext_vector_type(4))) _Float16 half4v;
typedef __attribute__((ext_vector_type(4))) float f32x4;

// ---------------- problem constants ----------------
constexpr int cB = 32, cNP = 2000, cS = 100, cL = 60, cE = 300;
constexpr int cQ = 50, cDD = 100, cDH = 50;
constexpr float cNEG = 1.0e12f;

// ---------------- workspace layout (float units) ----------------
constexpr size_t OFF_REL  = 0;        // B*Q*S = 160000
constexpr size_t OFF_RG   = 160000;   // B*Q*E = 480000 (fp32 gathered report emb)
constexpr size_t OFF_RNRM = 640000;   // B*Q
constexpr size_t OFF_IDFW = 641600;   // B*Q
constexpr size_t OFF_W1TH = 643200;   // 112*304 f16 = 17024 floats
constexpr size_t OFF_W1TL = 660224;   // 17024
constexpr size_t OFF_W2TH = 677248;   // 64*128 f16 = 4096 floats
constexpr size_t OFF_W2TL = 681344;   // 4096

// ---------------- LDS byte offsets (kernelA) ----------------
constexpr int LDS_CL    = 0;         // [60][300] f32
constexpr int LDS_AL    = 72000;     // [50][60] f32
constexpr int LDS_AVF   = 84000;     // [50][300] f32  (R[b] staged here during scores phase)
constexpr int LDS_G_HI  = 0;         // f16 [64 q][320 e] swizzled (overlays CL)
constexpr int LDS_G_LO  = 40960;     // rows are 640 B (multiple of 128 -> safe XOR swizzle)
constexpr int LDS_H1    = 84000;     // f32 [64][128] (overlays AVF)
constexpr int LDS_H2    = 116768;    // f32 [50][68]
constexpr int LDS_SCL   = 144000;    // f32 [64]
constexpr int LDS_WORDS = 144256;    // int [64]
constexpr int LDS_TOTAL = 144512;

__device__ __forceinline__ _Float16 h_hi(float f) { return (_Float16)f; }
__device__ __forceinline__ _Float16 h_lo(float f, _Float16 h) { return (_Float16)(f - (float)h); }
// block-local XOR swizzle: permutes only within each 128-byte block -> never leaves the row
__device__ __forceinline__ int bswz(int cb, int row) {
    return (cb & ~127) | ((cb & 127) ^ ((row & 7) << 4));
}

// ---------------- prep: pack W1^T, W2^T as fp16 hi/lo, zero-padded ----------------
__global__ void prep_weights(const float* __restrict__ W1, const float* __restrict__ W2,
                             _Float16* __restrict__ W1TH, _Float16* __restrict__ W1TL,
                             _Float16* __restrict__ W2TH, _Float16* __restrict__ W2TL)
{
    int tid = blockIdx.x * blockDim.x + threadIdx.x;
    int stride = gridDim.x * blockDim.x;
    for (int idx = tid; idx < 112 * 304; idx += stride) {
        int d = idx / 304, e = idx % 304;
        float w = (d < cDD && e < cE) ? W1[(size_t)e * cDD + d] : 0.f;
        _Float16 h = h_hi(w);
        W1TH[idx] = h; W1TL[idx] = h_lo(w, h);
    }
    for (int idx = tid; idx < 64 * 128; idx += stride) {
        int j = idx / 128, d = idx % 128;
        float w = (j < cDH && d < cDD) ? W2[(size_t)d * cDH + j] : 0.f;
        _Float16 h = h_hi(w);
        W2TH[idx] = h; W2TL[idx] = h_lo(w, h);
    }
}

// ---------------- prep per-batch: gather R fp32, norms, idf softmax ----------------
__global__ __launch_bounds__(256) void prep_batch(
    const int* __restrict__ r_idx,
    const float* __restrict__ report_table,
    const float* __restrict__ report_word_emb,
    const float* __restrict__ idf_table,
    float* __restrict__ Rg, float* __restrict__ rnorm, float* __restrict__ idfw)
{
    int b = blockIdx.x, tid = threadIdx.x;
    __shared__ int rv[cQ];
    if (tid < cQ) rv[tid] = (int)report_table[(size_t)r_idx[b] * cQ + tid];
    __syncthreads();
    float* dst = Rg + (size_t)b * cQ * cE;
    for (int idx = tid; idx < cQ * 75; idx += 256) {
        int q = idx / 75, e4 = idx % 75;
        f32x4 v = *(const f32x4*)(report_word_emb + (size_t)rv[q] * cE + e4 * 4);
        *(f32x4*)(dst + (size_t)q * cE + e4 * 4) = v;
    }
    __syncthreads();
    if (tid < cQ) {
        const float* row = dst + (size_t)tid * cE;
        float ss = 0.f;
        for (int e = 0; e < cE; e += 4) {
            f32x4 v = *(const f32x4*)(row + e);
            ss += v[0]*v[0] + v[1]*v[1] + v[2]*v[2] + v[3]*v[3];
        }
        rnorm[b * cQ + tid] = sqrtf(ss);
    }
    if (tid < 64) {
        float x = -INFINITY;
        if (tid < cQ) {
            float w = idf_table[rv[tid]];
            x = (w == 0.0f) ? -cNEG : w;
        }
        float m = x;
        for (int o = 32; o; o >>= 1) m = fmaxf(m, __shfl_xor(m, o));
        float e = (tid < cQ) ? expf(x - m) : 0.f;
        float ssum = e;
        for (int o = 32; o; o >>= 1) ssum += __shfl_xor(ssum, o);
        if (tid < cQ) idfw[b * cQ + tid] = e / ssum;
    }
}

// ---------------- main kernel: one block per (b, s), 1024 threads ----------------
// 1024 threads = 16 waves/CU = 4 waves/SIMD (LDS limits to 1 block/CU).
// R[b] is staged into LDS (AVF region, dead until AV phase) so the scores phase
// reads R via LDS broadcasts instead of 75x-repeated global loads.
// All per-output arithmetic sequences are IDENTICAL to previous versions
// (bit-exact output) -- only the thread->output assignment changed.
__global__ __launch_bounds__(1024, 4) void kernelA(
    const int* __restrict__ r_idx, const int* __restrict__ c_idx,
    const float* __restrict__ matrix, const float* __restrict__ code_table,
    const float* __restrict__ snippet_table, const float* __restrict__ code_word_emb,
    const float* __restrict__ snippet_len_table,
    const float* __restrict__ Rg, const float* __restrict__ rnorm,
    const _Float16* __restrict__ W1TH, const _Float16* __restrict__ W1TL, const float* __restrict__ b1,
    const _Float16* __restrict__ W2TH, const _Float16* __restrict__ W2TL, const float* __restrict__ b2,
    const float* __restrict__ W3, const float* __restrict__ b3,
    float* __restrict__ rel_out)
{
    const int s = blockIdx.x, b = blockIdx.y;
    const int tid = threadIdx.x;
    const int lane = tid & 63, wid = tid >> 6;
    const int n = lane & 15, gl = lane >> 4;     // MFMA fragment coords

    __shared__ __align__(16) unsigned char smem[LDS_TOTAL];
    int*   words = (int*)(smem + LDS_WORDS);
    float* sclp  = (float*)(smem + LDS_SCL);
    float* Cl    = (float*)(smem + LDS_CL);      // [60][300] fp32
    float* Alp   = (float*)(smem + LDS_AL);      // [50][60] fp32
    float* AVf   = (float*)(smem + LDS_AVF);     // [50][300] fp32 (R during scores)
    float* Rlds  = (float*)(smem + LDS_AVF);     // R[b] staged here for scores phase

    const int rr = r_idx[b], cc = c_idx[b];
    const int code = (int)matrix[(size_t)rr * cNP + cc];
    const int snip = (int)code_table[(size_t)code * cS + s];
    const int slen = (int)snippet_len_table[snip];

    if (tid < cL) words[tid] = (int)snippet_table[(size_t)snip * cL + tid];
    if (tid < cQ) sclp[tid] = 0.f;
    // stage R[b] (50x300 f32) into LDS -- no dependence on 'words'
    {
        const float* RgB = Rg + (size_t)b * cQ * cE;
        for (int idx = tid; idx < cQ * 75; idx += 1024) {
            int q = idx / 75, e4 = idx % 75;
            *(f32x4*)(Rlds + q * 300 + e4 * 4) = *(const f32x4*)(RgB + (size_t)q * cE + e4 * 4);
        }
    }
    __syncthreads();

    // ---- gather snippet embeddings: fp32 row-major [60][300]
    for (int idx = tid; idx < cL * 75; idx += 1024) {
        int l = idx / 75, e4 = idx % 75;
        f32x4 v = *(const f32x4*)(code_word_emb + (size_t)words[l] * cE + e4 * 4);
        *(f32x4*)(Cl + l * 300 + e4 * 4) = v;
    }
    __syncthreads();

    // ---- scores[q][l] = sum_e r[q][e]*C[l][e]  (round-1-exact fp32) ----
    // thread (qt = tid>>5, lt2 = tid&31) owns q = qt+32i (i<2), l = lt2+32j (j<2)
    // R read from LDS: within a wave, addresses are shared by 32 lanes (broadcast).
    {
        const int qt = tid >> 5, lt2 = tid & 31;
        float acc[2][2];
        #pragma unroll
        for (int i = 0; i < 2; i++)
            #pragma unroll
            for (int j = 0; j < 2; j++) acc[i][j] = 0.f;
        const float* rrow[2];
        #pragma unroll
        for (int i = 0; i < 2; i++) {
            int q = qt + 32 * i;
            rrow[i] = Rlds + (size_t)(q < cQ ? q : 0) * 300;
        }
        int lrow[2];
        #pragma unroll
        for (int j = 0; j < 2; j++) {
            int l = lt2 + 32 * j;
            lrow[j] = (l < cL) ? l : 0;
        }
        for (int e = 0; e < cE; e += 4) {
            f32x4 rv[2], cv[2];
            #pragma unroll
            for (int i = 0; i < 2; i++) rv[i] = *(const f32x4*)(rrow[i] + e);
            #pragma unroll
            for (int j = 0; j < 2; j++) cv[j] = *(const f32x4*)(Cl + lrow[j] * 300 + e);
            #pragma unroll
            for (int i = 0; i < 2; i++)
                #pragma unroll
                for (int j = 0; j < 2; j++)
                    acc[i][j] += rv[i][0] * cv[j][0] + rv[i][1] * cv[j][1] +
                                 rv[i][2] * cv[j][2] + rv[i][3] * cv[j][3];
        }
        #pragma unroll
        for (int i = 0; i < 2; i++) {
            int q = qt + 32 * i;
            if (q >= cQ) continue;
            #pragma unroll
            for (int j = 0; j < 2; j++) {
                int l = lt2 + 32 * j;
                if (l >= cL) continue;
                Alp[q * 60 + l] = acc[i][j] - ((l >= slen) ? cNEG : 0.f);
            }
        }
    }
    __syncthreads();

    // ---- softmax over l (round-1-exact; identical mapping & reduce order) ----
    {
        const int g2 = tid >> 2, k = tid & 3;
        if (g2 < cQ) {
            float v[15];
            float m = -INFINITY;
            #pragma unroll
            for (int t = 0; t < 15; t++) { v[t] = Alp[g2 * 60 + k + 4 * t]; m = fmaxf(m, v[t]); }
            m = fmaxf(m, __shfl_xor(m, 1));
            m = fmaxf(m, __shfl_xor(m, 2));
            float sum = 0.f;
            #pragma unroll
            for (int t = 0; t < 15; t++) { v[t] = expf(v[t] - m); sum += v[t]; }
            sum += __shfl_xor(sum, 1);
            sum += __shfl_xor(sum, 2);
            float inv = 1.0f / sum;
            #pragma unroll
            for (int t = 0; t < 15; t++) Alp[g2 * 60 + k + 4 * t] = v[t] * inv;
        }
    }
    __syncthreads();

    // ---- av[q][e] = sum_l a[q][l]*C[l][e] (round-1-exact fp32) ----
    // l-loop OUTER. thread (qt3 = tid>>5, et3 = tid&31) owns q = qt3+32i (i<2),
    // e4 = et3+32jj (jj<3). Overwrites the R staging area (R is dead here).
    {
        const int qt3 = tid >> 5, et3 = tid & 31;
        const float* arow[2];
        int qv[2];
        #pragma unroll
        for (int i = 0; i < 2; i++) {
            int q = qt3 + 32 * i;
            qv[i] = q;
            arow[i] = Alp + (size_t)((q < cQ) ? q : 0) * 60;
        }
        int e4v[3], e4c[3];
        #pragma unroll
        for (int jj = 0; jj < 3; jj++) {
            e4v[jj] = et3 + 32 * jj;
            e4c[jj] = (e4v[jj] < 75) ? e4v[jj] : 0;
        }
        f32x4 acc4[2][3];
        #pragma unroll
        for (int i = 0; i < 2; i++)
            #pragma unroll
            for (int jj = 0; jj < 3; jj++) acc4[i][jj] = (f32x4){0.f, 0.f, 0.f, 0.f};
        for (int l = 0; l < cL; l++) {
            float av[2];
            #pragma unroll
            for (int i = 0; i < 2; i++) av[i] = arow[i][l];
            f32x4 cv[3];
            #pragma unroll
            for (int jj = 0; jj < 3; jj++) cv[jj] = *(const f32x4*)(Cl + l * 300 + e4c[jj] * 4);
            #pragma unroll
            for (int i = 0; i < 2; i++)
                #pragma unroll
                for (int jj = 0; jj < 3; jj++) {
                    acc4[i][jj][0] += av[i] * cv[jj][0];
                    acc4[i][jj][1] += av[i] * cv[jj][1];
                    acc4[i][jj][2] += av[i] * cv[jj][2];
                    acc4[i][jj][3] += av[i] * cv[jj][3];
                }
        }
        #pragma unroll
        for (int i = 0; i < 2; i++)
            #pragma unroll
            for (int jj = 0; jj < 3; jj++)
                if (e4v[jj] < 75 && qv[i] < cQ)
                    *(f32x4*)(AVf + qv[i] * 300 + e4v[jj] * 4) = acc4[i][jj];
    }
    __syncthreads();

    // ---- sum-of-squares of av (EXACT old mapping + reduce order, reads back fp32) ----
    if (tid < 256) {
        const int qs = tid >> 4, es = tid & 15;
        #pragma unroll
        for (int jj = 0; jj < 5; jj++) {
            int e4 = es + 16 * jj;
            int e4cl = (e4 < 75) ? e4 : 0;
            #pragma unroll
            for (int i = 0; i < 4; i++) {
                int q = qs + 16 * i;
                int qcl = (q < cQ) ? q : 0;
                f32x4 v = *(const f32x4*)(AVf + qcl * 300 + e4cl * 4);
                bool valid = (e4 < 75) && (q < cQ);
                float dv = valid ? (v[0]*v[0] + v[1]*v[1] + v[2]*v[2] + v[3]*v[3]) : 0.f;
                dv += __shfl_xor(dv, 1);
                dv += __shfl_xor(dv, 2);
                dv += __shfl_xor(dv, 4);
                dv += __shfl_xor(dv, 8);
                if (es == 0 && q < cQ) sclp[q] += dv;
            }
        }
    }
    __syncthreads();

    // finalize scale = 1/(|r|*|av|)  (0-guard == reference NaN fix)
    if (tid < cQ) {
        float p = rnorm[b * cQ + tid] * sqrtf(sclp[tid]);
        sclp[tid] = (p > 0.f) ? (1.0f / p) : 0.f;
    }

    // ---- g = r .* av -> f16 hi/lo [64 q][320 e], block-swizzled rows of 640 B ----
    {
        const float* RgB = Rg + (size_t)b * cQ * cE;
        for (int idx = tid; idx < 64 * 80; idx += 1024) {
            int q = idx / 80, e4 = idx % 80;
            half4v h4 = {0, 0, 0, 0}, l4 = {0, 0, 0, 0};
            if (q < cQ && e4 < 75) {
                f32x4 av4 = *(const f32x4*)(AVf + q * 300 + e4 * 4);
                f32x4 rv4 = *(const f32x4*)(RgB + (size_t)q * cE + e4 * 4);
                #pragma unroll
                for (int k = 0; k < 4; k++) {
                    float gf = av4[k] * rv4[k];
                    h4[k] = h_hi(gf);
                    l4[k] = h_lo(gf, h4[k]);
                }
            }
            int bo = q * 640 + bswz(8 * e4, q);
            *(half4v*)(smem + LDS_G_HI + bo) = h4;
            *(half4v*)(smem + LDS_G_LO + bo) = l4;
        }
    }
    __syncthreads();

    // ---- h1 = tanh(scale*(g@W1)+b1): MFMA ----
    // 16 waves: wave owns d-tile dt = wid&7 (<7) and q-half qh = wid>>3 (q2 in {2qh, 2qh+1})
    {
        const half8 z8 = {0,0,0,0,0,0,0,0};
        const int dt = wid & 7;
        const int q2b = (wid >> 3) * 2;
        f32x4 accH[2];
        #pragma unroll
        for (int t = 0; t < 2; t++) accH[t] = (f32x4){0.f, 0.f, 0.f, 0.f};
        if (dt < 7) {
            #pragma unroll
            for (int ks = 0; ks < 10; ks++) {
                bool lv = (ks != 9) || (gl < 2);
                half8 gh[2], glo[2];
                #pragma unroll
                for (int t = 0; t < 2; t++) {
                    gh[t] = z8; glo[t] = z8;
                    if (lv) {
                        int q = 16 * (q2b + t) + n;
                        int bo = q * 640 + bswz(64 * ks + 16 * gl, q);
                        gh[t]  = *(const half8*)(smem + LDS_G_HI + bo);
                        glo[t] = *(const half8*)(smem + LDS_G_LO + bo);
                    }
                }
                half8 wh = z8, wl = z8;
                if (lv) {
                    int d = 16 * dt + n;
                    wh = *(const half8*)(W1TH + (size_t)d * 304 + 32 * ks + 8 * gl);
                    wl = *(const half8*)(W1TL + (size_t)d * 304 + 32 * ks + 8 * gl);
                }
                #pragma unroll
                for (int t = 0; t < 2; t++) {
                    accH[t] = __builtin_amdgcn_mfma_f32_16x16x32_f16(gh[t],  wh, accH[t], 0, 0, 0);
                    accH[t] = __builtin_amdgcn_mfma_f32_16x16x32_f16(gh[t],  wl, accH[t], 0, 0, 0);
                    accH[t] = __builtin_amdgcn_mfma_f32_16x16x32_f16(glo[t], wh, accH[t], 0, 0, 0);
                }
            }
        }
        float* h1p = (float*)(smem + LDS_H1);
        if (dt < 7) {
            int d = 16 * dt + n;
            #pragma unroll
            for (int t = 0; t < 2; t++)
                #pragma unroll
                for (int r = 0; r < 4; r++) {
                    int q = 16 * (q2b + t) + 4 * gl + r;
                    if (q < cQ) {
                        float v = (d < cDD) ? tanhf(accH[t][r] * sclp[q] + b1[d]) : 0.f;
                        h1p[q * 128 + d] = v;
                    }
                }
        }
        for (int idx = tid; idx < cQ * 16; idx += 1024) {     // zero cols 112..127
            int q = idx >> 4, d = 112 + (idx & 15);
            h1p[q * 128 + d] = 0.f;
        }
    }
    __syncthreads();

    // ---- h2 = tanh(h1@W2+b2): MFMA; 16 waves: j-tile = wid&3, q2 = wid>>2 ----
    {
        const float* h1p = (const float*)(smem + LDS_H1);
        const int jw = 16 * (wid & 3) + n;
        const int q2 = wid >> 2;
        f32x4 accJ = (f32x4){0.f, 0.f, 0.f, 0.f};
        #pragma unroll
        for (int ks = 0; ks < 4; ks++) {
            int q = 16 * q2 + n;
            const float* p = h1p + q * 128 + 32 * ks + 8 * gl;
            f32x4 fa = *(const f32x4*)p;
            f32x4 fb = *(const f32x4*)(p + 4);
            half8 h8, l8;
            #pragma unroll
            for (int jj = 0; jj < 8; jj++) {
                float f = (jj < 4) ? fa[jj] : fb[jj - 4];
                _Float16 h = h_hi(f);
                h8[jj] = h;
                l8[jj] = h_lo(f, h);
            }
            half8 wh = *(const half8*)(W2TH + (size_t)jw * 128 + 32 * ks + 8 * gl);
            half8 wl = *(const half8*)(W2TL + (size_t)jw * 128 + 32 * ks + 8 * gl);
            accJ = __builtin_amdgcn_mfma_f32_16x16x32_f16(h8, wh, accJ, 0, 0, 0);
            accJ = __builtin_amdgcn_mfma_f32_16x16x32_f16(h8, wl, accJ, 0, 0, 0);
            accJ = __builtin_amdgcn_mfma_f32_16x16x32_f16(l8, wh, accJ, 0, 0, 0);
        }
        float* h2p = (float*)(smem + LDS_H2);
        #pragma unroll
        for (int r = 0; r < 4; r++) {
            int q = 16 * q2 + 4 * gl + r;
            if (q < cQ && jw < cDH) h2p[q * 68 + jw] = tanhf(accJ[r] + b2[jw]);
        }
    }
    __syncthreads();

    // ---- rel[q] = tanh(h2 @ W3 + b3) ----
    if (tid < cQ) {
        const float* h2p = (const float*)(smem + LDS_H2);
        float a = b3[0];
        #pragma unroll 10
        for (int jj = 0; jj < cDH; jj++) a += h2p[tid * 68 + jj] * W3[jj];
        rel_out[((size_t)b * cQ + tid) * cS + s] = tanhf(a);
    }
}

// ---------------- per-batch: c_mask, top-5, Wk fusion, idf-weighted sum ----------------
__global__ __launch_bounds__(64) void kernelB(
    const float* __restrict__ rel_ws, const float* __restrict__ idfw,
    const int* __restrict__ c_idx, const float* __restrict__ code_len_table,
    const float* __restrict__ Wk, const float* __restrict__ bk,
    float* __restrict__ out)
{
    int b = blockIdx.x, q = threadIdx.x;
    float val = 0.f;
    if (q < cQ) {
        int clen = (int)code_len_table[c_idx[b]];
        const float* row = rel_ws + ((size_t)b * cQ + q) * cS;
        float t0 = -INFINITY, t1 = -INFINITY, t2 = -INFINITY, t3 = -INFINITY, t4 = -INFINITY;
        for (int s = 0; s < cS; s++) {
            float v = row[s] * ((s < clen) ? 1.f : 0.f);
            float m0 = fmaxf(t0, v), n0 = fminf(t0, v);
            float m1 = fmaxf(t1, n0), n1 = fminf(t1, n0);
            float m2 = fmaxf(t2, n1), n2 = fminf(t2, n1);
            float m3 = fmaxf(t3, n2), n3 = fminf(t3, n2);
            float m4 = fmaxf(t4, n3);
            t0 = m0; t1 = m1; t2 = m2; t3 = m3; t4 = m4;
        }
        float rc = t0 * Wk[0] + t1 * Wk[1] + t2 * Wk[2] + t3 * Wk[3] + t4 * Wk[4] + bk[0];
        val = rc * idfw[b * cQ + q];
    }
    for (int o = 32; o; o >>= 1) val += __shfl_down(val, o);
    if (q == 0) out[b] = val;
}

extern "C" void kernel_launch(void* const* d_in, const int* in_sizes, int n_in,
                              void* d_out, int out_size, void* d_ws, size_t ws_size,
                              hipStream_t stream)
{
    const int*   r_idx             = (const int*)d_in[0];
    const int*   c_idx             = (const int*)d_in[1];
    const float* matrix            = (const float*)d_in[2];
    const float* report_table      = (const float*)d_in[3];
    const float* report_word_emb   = (const float*)d_in[4];
    const float* idf_table         = (const float*)d_in[5];
    const float* code_table        = (const float*)d_in[6];
    const float* snippet_table     = (const float*)d_in[7];
    const float* code_word_emb     = (const float*)d_in[8];
    const float* snippet_len_table = (const float*)d_in[9];
    const float* code_len_table    = (const float*)d_in[10];
    const float* W1 = (const float*)d_in[11];
    const float* b1 = (const float*)d_in[12];
    const float* W2 = (const float*)d_in[13];
    const float* b2 = (const float*)d_in[14];
    const float* W3 = (const float*)d_in[15];
    const float* b3 = (const float*)d_in[16];
    const float* Wk = (const float*)d_in[17];
    const float* bk = (const float*)d_in[18];
    float* out = (float*)d_out;
    float* ws  = (float*)d_ws;

    float* rel_ws = ws + OFF_REL;
    float* Rg     = ws + OFF_RG;
    float* rnormp = ws + OFF_RNRM;
    float* idfwp  = ws + OFF_IDFW;
    _Float16* W1THp = (_Float16*)(ws + OFF_W1TH);
    _Float16* W1TLp = (_Float16*)(ws + OFF_W1TL);
    _Float16* W2THp = (_Float16*)(ws + OFF_W2TH);
    _Float16* W2TLp = (_Float16*)(ws + OFF_W2TL);

    prep_weights<<<64, 256, 0, stream>>>(W1, W2, W1THp, W1TLp, W2THp, W2TLp);
    prep_batch<<<cB, 256, 0, stream>>>(r_idx, report_table, report_word_emb, idf_table,
                                       Rg, rnormp, idfwp);
    kernelA<<<dim3(cS, cB), 1024, 0, stream>>>(r_idx, c_idx, matrix, code_table,
                                               snippet_table, code_word_emb, snippet_len_table,
                                               Rg, rnormp,
                                               W1THp, W1TLp, b1, W2THp, W2TLp, b2, W3, b3, rel_ws);
    kernelB<<<cB, 64, 0, stream>>>(rel_ws, idfwp, c_idx, code_len_table, Wk, bk, out);
}